// Round 7
// baseline (545.728 us; speedup 1.0000x reference)
//
#include <hip/hip_runtime.h>

#define N_TOK 4096
#define DIM   1024

typedef __bf16 bf16x8 __attribute__((ext_vector_type(8)));
typedef float  f32x4  __attribute__((ext_vector_type(4)));

__device__ __forceinline__ unsigned short f2bf(float f) {
  union { float f; unsigned u; } v; v.f = f;
  unsigned u = v.u;
  return (unsigned short)((u + 0x7fffu + ((u >> 16) & 1u)) >> 16);
}
__device__ __forceinline__ float bf2f(unsigned short h) {
  union { unsigned u; float f; } v; v.u = ((unsigned)h) << 16;
  return v.f;
}

// ---------------------------------------------------------------------------
// f32 -> bf16 convert (x)
// ---------------------------------------------------------------------------
__global__ void cvt_f32_bf16(const float* __restrict__ x,
                             unsigned short* __restrict__ o) {
  int i = (blockIdx.x * 256 + threadIdx.x) * 4;
  float4 v = *(const float4*)(x + i);
  ushort4 r;
  r.x = f2bf(v.x); r.y = f2bf(v.y); r.z = f2bf(v.z); r.w = f2bf(v.w);
  *(ushort4*)(o + i) = r;
}

// ---------------------------------------------------------------------------
// Transpose 1024x1024 f32 -> bf16 (Wt[n][k] = W[k][n])
// ---------------------------------------------------------------------------
__global__ void transpose_cvt(const float* __restrict__ W,
                              unsigned short* __restrict__ Wt) {
  __shared__ float tile[32][33];
  int bx = blockIdx.x * 32, by = blockIdx.y * 32;
  int tx = threadIdx.x, ty = threadIdx.y;
  for (int r = ty; r < 32; r += 8)
    tile[r][tx] = W[(size_t)(by + r) * DIM + bx + tx];
  __syncthreads();
  for (int r = ty; r < 32; r += 8)
    Wt[(size_t)(bx + r) * DIM + by + tx] = f2bf(tile[tx][r]);
}

// ---------------------------------------------------------------------------
// bf16 transpose: Vt[n][m] = V[m][n]
// ---------------------------------------------------------------------------
__global__ void transpose_bf16(const unsigned short* __restrict__ V, int ldv,
                               unsigned short* __restrict__ Vt, int ldvt) {
  __shared__ unsigned short tile[32][33];
  int bx = blockIdx.x * 32;  // n
  int by = blockIdx.y * 32;  // m
  int tx = threadIdx.x, ty = threadIdx.y;
  for (int r = ty; r < 32; r += 8)
    tile[r][tx] = V[(size_t)(by + r) * ldv + bx + tx];
  __syncthreads();
  for (int r = ty; r < 32; r += 8)
    Vt[(size_t)(bx + r) * ldvt + by + tx] = tile[tx][r];
}

// ---------------------------------------------------------------------------
// Concatenated, pre-scaled bias: ball[0:1024)=bq/32, [1024:2048)=bk, rest=bv
// ---------------------------------------------------------------------------
__global__ void make_bias(const float* __restrict__ bq,
                          const float* __restrict__ bk,
                          const float* __restrict__ bv,
                          float* __restrict__ ball) {
  int i = blockIdx.x * 256 + threadIdx.x;
  float v = (i < 1024) ? bq[i] * 0.03125f
                       : ((i < 2048) ? bk[i - 1024] : bv[i - 2048]);
  ball[i] = v;
}

// ---------------------------------------------------------------------------
// zero-fill f32 (out for atomicAdd epilogue; Lsum for row-sum atomics)
// ---------------------------------------------------------------------------
__global__ void zero_f32(float* __restrict__ p) {
  ((float4*)p)[blockIdx.x * 256 + threadIdx.x] = make_float4(0.f, 0.f, 0.f, 0.f);
}

// ---------------------------------------------------------------------------
// A·B^T MFMA GEMM: C[m][n] = sum_k A[m][k]*B[n][k]
// 128x128 tile, 4 waves, BK=64. Staging is register-pipelined: next tile's
// global loads issue right after the compute barrier, consumed at the NEXT
// iteration's ds_write -> global latency overlaps the MFMA phase.
// __launch_bounds__(256,3): VGPR budget ~170 so the ~130-reg working set
// (64 acc + 32 stage + 16 frag + addr) does NOT spill (round-6 failure:
// default 64-VGPR cap spilled staging regs -> 135 MB scratch traffic).
// LDS stride 72 (per-lane ds_write allows padding) -> conflict-free reads.
// EPI 0: concat QKV projection. bf16 store, acc*colscale + ball[gc].
// EPI 2: S-phase. U = exp(score) causal (col>row -> 0), bf16 store, skip
//        bn>bm; row sums of U block-reduced then atomicAdd into Lsum.
// EPI 3: O = (U V)/L[row]. split-K over blockIdx.z (1024-wide chunks clipped
//        to Keff=(bm+1)*128); direct store if single chunk else atomicAdd.
// ---------------------------------------------------------------------------
#define BK 64
#define LDS_STRIDE 72

template <int EPI>
__global__ __launch_bounds__(256, 3)
void gemm_tn(const unsigned short* __restrict__ A,
             const unsigned short* __restrict__ B,
             void* __restrict__ Cout,
             const float* __restrict__ bias,
             float* __restrict__ Lsum,
             int K, int lda, int ldb, int ldc) {
  int bm, bn, kbeg, kend;
  bool single = true;
  if (EPI == 3) {
    bn = blockIdx.x; bm = blockIdx.y;
    const int Keff = (bm + 1) * 128;
    kbeg = blockIdx.z * 1024;
    if (kbeg >= Keff) return;
    kend = min(kbeg + 1024, Keff);
    single = (Keff <= 1024);
  } else {
    bm = blockIdx.y; bn = blockIdx.x;
    if (EPI == 2 && bn > bm) return;
    kbeg = 0; kend = K;
  }

  __shared__ __align__(16) unsigned short smA[128 * LDS_STRIDE];
  __shared__ __align__(16) unsigned short smB[128 * LDS_STRIDE];

  const int t = threadIdx.x;
  const int lane = t & 63, w = t >> 6;
  const int wm = (w & 1) * 64, wn = (w >> 1) * 64;

  f32x4 acc[4][4] = {};

  const unsigned short* Ab = A + (size_t)bm * 128 * lda;
  const unsigned short* Bb = B + (size_t)bn * 128 * ldb;

  const int rA = wm + (lane & 15);
  const int rB = wn + (lane & 15);
  const int kquad = (lane >> 4) << 3;

  // Staging geometry: chunk c covers rows c*32+tr (tr=t>>3), cols tg..tg+8.
  const int tr = t >> 3;
  const int tg = (t & 7) << 3;

  float4 ra[4], rb[4];
  // prologue: load first tile into registers
#pragma unroll
  for (int c = 0; c < 4; c++) {
    const int r = c * 32 + tr;
    ra[c] = *(const float4*)(Ab + (size_t)r * lda + kbeg + tg);
    rb[c] = *(const float4*)(Bb + (size_t)r * ldb + kbeg + tg);
  }

  for (int k0 = kbeg; k0 < kend; k0 += BK) {
    __syncthreads();  // prior compute phase's LDS reads complete
#pragma unroll
    for (int c = 0; c < 4; c++) {
      const int r = c * 32 + tr;
      *(float4*)(&smA[r * LDS_STRIDE + tg]) = ra[c];
      *(float4*)(&smB[r * LDS_STRIDE + tg]) = rb[c];
    }
    __syncthreads();  // tiles visible to all waves

    // issue next tile's loads NOW; they land during the MFMA phase below
    const int kn = k0 + BK;
    if (kn < kend) {
#pragma unroll
      for (int c = 0; c < 4; c++) {
        const int r = c * 32 + tr;
        ra[c] = *(const float4*)(Ab + (size_t)r * lda + kn + tg);
        rb[c] = *(const float4*)(Bb + (size_t)r * ldb + kn + tg);
      }
    }

#pragma unroll
    for (int kk = 0; kk < BK; kk += 32) {
      bf16x8 af[4], bfr[4];
      const int kof = kk + kquad;
#pragma unroll
      for (int i = 0; i < 4; i++)
        af[i] = *(const bf16x8*)(&smA[(rA + i * 16) * LDS_STRIDE + kof]);
#pragma unroll
      for (int j = 0; j < 4; j++)
        bfr[j] = *(const bf16x8*)(&smB[(rB + j * 16) * LDS_STRIDE + kof]);
#pragma unroll
      for (int i = 0; i < 4; i++)
#pragma unroll
        for (int j = 0; j < 4; j++)
          acc[i][j] = __builtin_amdgcn_mfma_f32_16x16x32_bf16(af[i], bfr[j],
                                                              acc[i][j], 0, 0, 0);
    }
  }

  // Epilogues. C/D layout: col = lane&15, row = (lane>>4)*4 + reg.
  float* Cf = (float*)Cout;
  unsigned short* Ch = (unsigned short*)Cout;
  const int colbase = bn * 128 + wn + (lane & 15);
  const int rowbase = bm * 128 + wm + ((lane >> 4) << 2);

  if (EPI == 0) {
#pragma unroll
    for (int i = 0; i < 4; i++)
#pragma unroll
      for (int j = 0; j < 4; j++) {
        const int gc = colbase + j * 16;
        const float cs = (gc < 1024) ? 0.03125f : 1.0f;
#pragma unroll
        for (int r = 0; r < 4; r++) {
          const int gr = rowbase + i * 16 + r;
          Ch[(size_t)gr * ldc + gc] = f2bf(acc[i][j][r] * cs + bias[gc]);
        }
      }
  } else if (EPI == 2) {
    // U = exp(score), causal; block row-sum -> atomicAdd into Lsum.
    __syncthreads();                 // all LDS reads done; repurpose smA
    float* Lp = (float*)smA;         // 128 floats
    if (t < 128) Lp[t] = 0.f;
    __syncthreads();
#pragma unroll
    for (int i = 0; i < 4; i++)
#pragma unroll
      for (int r = 0; r < 4; r++) {
        const int gr = rowbase + i * 16 + r;
        float sj = 0.f;
#pragma unroll
        for (int j = 0; j < 4; j++) {
          const int gc = colbase + j * 16;
          unsigned short h = 0;
          if (gc <= gr) h = f2bf(__expf(acc[i][j][r]));
          Ch[(size_t)gr * ldc + gc] = h;
          sj += bf2f(h);  // sum the rounded value so L matches stored U
        }
        sj += __shfl_xor(sj, 1);
        sj += __shfl_xor(sj, 2);
        sj += __shfl_xor(sj, 4);
        sj += __shfl_xor(sj, 8);
        if ((lane & 15) == 0)
          atomicAdd(&Lp[wm + ((lane >> 4) << 2) + i * 16 + r], sj);
      }
    __syncthreads();
    if (t < 128) atomicAdd(&Lsum[bm * 128 + t], Lp[t]);
  } else {
#pragma unroll
    for (int i = 0; i < 4; i++)
#pragma unroll
      for (int r = 0; r < 4; r++) {
        const int gr = rowbase + i * 16 + r;
        const float linv = 1.0f / Lsum[gr];
#pragma unroll
        for (int j = 0; j < 4; j++) {
          const int gc = colbase + j * 16;
          const float v = acc[i][j][r] * linv;
          if (single)
            Cf[(size_t)gr * ldc + gc] = v;
          else
            atomicAdd(&Cf[(size_t)gr * ldc + gc], v);
        }
      }
  }
}

// ---------------------------------------------------------------------------
// kernel_launch — ws layout (ushort elems):
//   [0,4M)    xb [4096x1024]; after concat GEMM, reused as V^T [1024x4096]
//   [4M,7M)   W_all^T = Wq^T | Wk^T | Wv^T  (3072 x 1024)
//   [7M,19M)  Call [4096x3072] = Q | K | V  (Q pre-scaled by 1/32)
//   [19M,35M) Sb [4096x4096]  (U = exp scores)
//   [35M,..)  ball [3072] f32, Lsum [4096] f32
// ---------------------------------------------------------------------------
extern "C" void kernel_launch(void* const* d_in, const int* in_sizes, int n_in,
                              void* d_out, int out_size, void* d_ws,
                              size_t ws_size, hipStream_t stream) {
  (void)in_sizes; (void)n_in; (void)out_size; (void)ws_size;
  const float* x  = (const float*)d_in[0];
  const float* Wq = (const float*)d_in[1];
  const float* bq = (const float*)d_in[2];
  const float* Wk = (const float*)d_in[3];
  const float* bk = (const float*)d_in[4];
  const float* Wv = (const float*)d_in[5];
  const float* bv = (const float*)d_in[6];
  float* out = (float*)d_out;

  const size_t M1 = (size_t)1024 * 1024;
  unsigned short* xb   = (unsigned short*)d_ws;   // 4M elems; later V^T
  unsigned short* Wt   = xb + 4 * M1;             // 3M elems
  unsigned short* Call = Wt + 3 * M1;             // 12M elems
  unsigned short* Sb   = Call + 12 * M1;          // 16M elems
  float* ball          = (float*)(Sb + 16 * M1);  // 3072 f32
  float* Lsum          = ball + 3072;             // 4096 f32

  // zeros first (off the critical GEMM chain)
  zero_f32<<<(N_TOK * DIM) / 1024, 256, 0, stream>>>(out);
  zero_f32<<<4, 256, 0, stream>>>(Lsum);
  make_bias<<<12, 256, 0, stream>>>(bq, bk, bv, ball);
  cvt_f32_bf16<<<(N_TOK * DIM) / 1024, 256, 0, stream>>>(x, xb);
  dim3 tb(32, 8);
  transpose_cvt<<<dim3(32, 32), tb, 0, stream>>>(Wq, Wt);
  transpose_cvt<<<dim3(32, 32), tb, 0, stream>>>(Wk, Wt + M1);
  transpose_cvt<<<dim3(32, 32), tb, 0, stream>>>(Wv, Wt + 2 * M1);

  // Call = x @ [Wq|Wk|Wv] + ball. 768 blocks.
  gemm_tn<0><<<dim3(24, 32), 256, 0, stream>>>(xb, Wt, Call, ball, nullptr,
                                               DIM, DIM, DIM, 3 * DIM);
  // V^T into the dead xb slot.
  transpose_bf16<<<dim3(32, 128), tb, 0, stream>>>(Call + 2048, 3 * DIM, xb,
                                                   N_TOK);
  // U = exp(Q K^T) causal + row sums Lsum.
  gemm_tn<2><<<dim3(32, 32), 256, 0, stream>>>(Call, Call + 1024, Sb, nullptr,
                                               Lsum, DIM, 3 * DIM, 3 * DIM,
                                               N_TOK);
  // O = (U V) / L, split-K over z (4 chunks of 1024) -> 640 active blocks.
  gemm_tn<3><<<dim3(8, 32, 4), 256, 0, stream>>>(Sb, xb, out, nullptr, Lsum,
                                                 N_TOK, N_TOK, N_TOK, DIM);
}

// Round 9
// 222.925 us; speedup vs baseline: 2.4480x; 2.4480x over previous
//
#include <hip/hip_runtime.h>

#define N_TOK 4096
#define DIM   1024

typedef __bf16 bf16x8 __attribute__((ext_vector_type(8)));
typedef float  f32x4  __attribute__((ext_vector_type(4)));

__device__ __forceinline__ unsigned short f2bf(float f) {
  union { float f; unsigned u; } v; v.f = f;
  unsigned u = v.u;
  return (unsigned short)((u + 0x7fffu + ((u >> 16) & 1u)) >> 16);
}
__device__ __forceinline__ float bf2f(unsigned short h) {
  union { unsigned u; float f; } v; v.u = ((unsigned)h) << 16;
  return v.f;
}

// async global->LDS, 16 B/lane: lane's data lands at (uniform lds base) + lane*16
__device__ __forceinline__ void gll16(const unsigned short* g,
                                      unsigned short* l) {
  __builtin_amdgcn_global_load_lds(
      (const __attribute__((address_space(1))) unsigned int*)g,
      (__attribute__((address_space(3))) unsigned int*)l, 16, 0, 0);
}

// ---------------------------------------------------------------------------
// Fused prep kernel — all independent pre-GEMM work in ONE launch:
//   job CVT  [0,2048):     xb = bf16(x), 8 elems/thread
//   job TQ/TK/TV (+1024):  Wt[n][k] = bf16(W[k][n]) via 32x32 LDS tile
//   job ZERO [5120,5888):  out rows 1024..4096 = 0  (768 blk * 256 thr *
//                          4 float4 = 786432 float4 = 3M floats, EXACT —
//                          round-8 bug was 3072 blocks = 4x OOB write)
//   job LSUM [5888,5892):  Lsum = 0
//   job BIAS [5892,5895):  ball = {bq/32, bk, bv}
// ---------------------------------------------------------------------------
#define PB_CVT 0
#define PB_TQ 2048
#define PB_ZERO 5120
#define PB_LSUM 5888
#define PB_BIAS 5892
#define PB_TOTAL 5895

__global__ void prep(const float* __restrict__ x, const float* __restrict__ Wq,
                     const float* __restrict__ Wk, const float* __restrict__ Wv,
                     const float* __restrict__ bq, const float* __restrict__ bk,
                     const float* __restrict__ bv,
                     unsigned short* __restrict__ xb,
                     unsigned short* __restrict__ Wt,
                     float* __restrict__ out, float* __restrict__ ball,
                     float* __restrict__ Lsum) {
  const int b = blockIdx.x;
  const int t = threadIdx.x;
  if (b < PB_TQ) {  // CVT
    const int i = ((b - PB_CVT) * 256 + t) * 8;
    float4 v0 = *(const float4*)(x + i);
    float4 v1 = *(const float4*)(x + i + 4);
    ushort4 r0, r1;
    r0.x = f2bf(v0.x); r0.y = f2bf(v0.y); r0.z = f2bf(v0.z); r0.w = f2bf(v0.w);
    r1.x = f2bf(v1.x); r1.y = f2bf(v1.y); r1.z = f2bf(v1.z); r1.w = f2bf(v1.w);
    *(ushort4*)(xb + i) = r0;
    *(ushort4*)(xb + i + 4) = r1;
  } else if (b < PB_ZERO) {  // transpose one 32x32 tile of one W
    const int which = (b - PB_TQ) >> 10;          // 0,1,2
    const int lb = (b - PB_TQ) & 1023;
    const float* W = (which == 0) ? Wq : (which == 1) ? Wk : Wv;
    unsigned short* D = Wt + (size_t)which * 1024 * 1024;
    __shared__ float tile[32][33];
    const int bx = (lb & 31) * 32, by = (lb >> 5) * 32;
    const int tx = t & 31, ty = t >> 5;  // ty in 0..7
    for (int r = ty; r < 32; r += 8)
      tile[r][tx] = W[(size_t)(by + r) * DIM + bx + tx];
    __syncthreads();
    for (int r = ty; r < 32; r += 8)
      D[(size_t)(bx + r) * DIM + by + tx] = f2bf(tile[tx][r]);
  } else if (b < PB_LSUM) {  // zero out rows >= 1024 (3M floats)
    float4* p = (float4*)(out + (size_t)1024 * DIM);
    const int i = ((b - PB_ZERO) * 256 + t) * 4;
#pragma unroll
    for (int c = 0; c < 4; c++) p[i + c] = make_float4(0.f, 0.f, 0.f, 0.f);
  } else if (b < PB_BIAS) {  // Lsum zero
    const int i = ((b - PB_LSUM) * 256 + t) * 4;
    *(float4*)(Lsum + i) = make_float4(0.f, 0.f, 0.f, 0.f);
  } else {  // bias, 4/thread
    const int i = ((b - PB_BIAS) * 256 + t) * 4;
#pragma unroll
    for (int c = 0; c < 4; c++) {
      const int k = i + c;
      if (k < 3072)
        ball[k] = (k < 1024) ? bq[k] * 0.03125f
                             : ((k < 2048) ? bk[k - 1024] : bv[k - 2048]);
    }
  }
}

// ---------------------------------------------------------------------------
// bf16 transpose: Vt[n][m] = V[m][n]  (V = Call's V columns)
// ---------------------------------------------------------------------------
__global__ void transpose_bf16(const unsigned short* __restrict__ V, int ldv,
                               unsigned short* __restrict__ Vt, int ldvt) {
  __shared__ unsigned short tile[32][33];
  int bx = blockIdx.x * 32;  // n
  int by = blockIdx.y * 32;  // m
  int tx = threadIdx.x, ty = threadIdx.y;
  for (int r = ty; r < 32; r += 8)
    tile[r][tx] = V[(size_t)(by + r) * ldv + bx + tx];
  __syncthreads();
  for (int r = ty; r < 32; r += 8)
    Vt[(size_t)(bx + r) * ldvt + by + tx] = tile[tx][r];
}

// ---------------------------------------------------------------------------
// A·B^T MFMA GEMM (round-4/5 proven): 128x128 tile, 4 waves, BK=64,
// global_load_lds(16B) staging, contiguous 128x64 LDS (m97 layout).
// EPI 0: concat QKV projection. bf16 store, acc*colscale + ball[gc].
// EPI 2: S-phase. U = exp(score) causal (col>row -> 0), bf16 store, skip
//        bn>bm; row sums of U block-reduced then atomicAdd into Lsum.
// EPI 3: O = (U V)/L[row]. split-K over blockIdx.z (1024-wide chunks clipped
//        to Keff=(bm+1)*128); direct store if single chunk else atomicAdd.
// ---------------------------------------------------------------------------
#define BK 64

template <int EPI>
__global__ void gemm_tn(const unsigned short* __restrict__ A,
                        const unsigned short* __restrict__ B,
                        void* __restrict__ Cout,
                        const float* __restrict__ bias,
                        float* __restrict__ Lsum,
                        int K, int lda, int ldb, int ldc) {
  int bm, bn, kbeg, kend;
  bool single = true;
  if (EPI == 3) {
    bn = blockIdx.x; bm = blockIdx.y;
    const int Keff = (bm + 1) * 128;
    kbeg = blockIdx.z * 1024;
    if (kbeg >= Keff) return;
    kend = min(kbeg + 1024, Keff);
    single = (Keff <= 1024);
  } else {
    bm = blockIdx.y; bn = blockIdx.x;
    if (EPI == 2 && bn > bm) return;
    kbeg = 0; kend = K;
  }

  __shared__ __align__(16) unsigned short smA[128 * 64];
  __shared__ __align__(16) unsigned short smB[128 * 64];

  const int t = threadIdx.x;
  const int lane = t & 63, w = t >> 6;
  const int wm = (w & 1) * 64, wn = (w >> 1) * 64;

  f32x4 acc[4][4] = {};

  const unsigned short* Ab = A + (size_t)bm * 128 * lda;
  const unsigned short* Bb = B + (size_t)bn * 128 * ldb;

  const int rA = wm + (lane & 15);
  const int rB = wn + (lane & 15);
  const int kquad = (lane >> 4) << 3;

  // staging source: row lr = lane>>3, k-chunk (lane&7)*8
  const int lr = lane >> 3;
  const int g8 = (lane & 7) << 3;
  const unsigned short* pa = Ab + (size_t)lr * lda + g8 + kbeg;
  const unsigned short* pb = Bb + (size_t)lr * ldb + g8 + kbeg;

  for (int k0 = kbeg; k0 < kend; k0 += BK) {
    __syncthreads();
#pragma unroll
    for (int m = 0; m < 4; m++) {
      const int r0 = (w << 5) + (m << 3);  // wave-uniform LDS row base
      gll16(pa + (size_t)r0 * lda, smA + r0 * 64);
      gll16(pb + (size_t)r0 * ldb, smB + r0 * 64);
    }
    pa += BK; pb += BK;
    __syncthreads();  // drains vmcnt -> tiles resident

#pragma unroll
    for (int kk = 0; kk < BK; kk += 32) {
      bf16x8 af[4], bfr[4];
      const int kof = kk + kquad;
#pragma unroll
      for (int i = 0; i < 4; i++)
        af[i] = *(const bf16x8*)(&smA[(rA + i * 16) * 64 + kof]);
#pragma unroll
      for (int j = 0; j < 4; j++)
        bfr[j] = *(const bf16x8*)(&smB[(rB + j * 16) * 64 + kof]);
#pragma unroll
      for (int i = 0; i < 4; i++)
#pragma unroll
        for (int j = 0; j < 4; j++)
          acc[i][j] = __builtin_amdgcn_mfma_f32_16x16x32_bf16(af[i], bfr[j],
                                                              acc[i][j], 0, 0, 0);
    }
  }

  // Epilogues. C/D layout: col = lane&15, row = (lane>>4)*4 + reg.
  float* Cf = (float*)Cout;
  unsigned short* Ch = (unsigned short*)Cout;
  const int colbase = bn * 128 + wn + (lane & 15);
  const int rowbase = bm * 128 + wm + ((lane >> 4) << 2);

  if (EPI == 0) {
#pragma unroll
    for (int i = 0; i < 4; i++)
#pragma unroll
      for (int j = 0; j < 4; j++) {
        const int gc = colbase + j * 16;
        const float cs = (gc < 1024) ? 0.03125f : 1.0f;
#pragma unroll
        for (int r = 0; r < 4; r++) {
          const int gr = rowbase + i * 16 + r;
          Ch[(size_t)gr * ldc + gc] = f2bf(acc[i][j][r] * cs + bias[gc]);
        }
      }
  } else if (EPI == 2) {
    // U = exp(score), causal; block row-sum -> atomicAdd into Lsum.
    __syncthreads();                 // all LDS reads done; repurpose smA
    float* Lp = (float*)smA;         // 128 floats
    if (t < 128) Lp[t] = 0.f;
    __syncthreads();
#pragma unroll
    for (int i = 0; i < 4; i++)
#pragma unroll
      for (int r = 0; r < 4; r++) {
        const int gr = rowbase + i * 16 + r;
        float sj = 0.f;
#pragma unroll
        for (int j = 0; j < 4; j++) {
          const int gc = colbase + j * 16;
          unsigned short h = 0;
          if (gc <= gr) h = f2bf(__expf(acc[i][j][r]));
          Ch[(size_t)gr * ldc + gc] = h;
          sj += bf2f(h);  // sum the rounded value so L matches stored U
        }
        sj += __shfl_xor(sj, 1);
        sj += __shfl_xor(sj, 2);
        sj += __shfl_xor(sj, 4);
        sj += __shfl_xor(sj, 8);
        if ((lane & 15) == 0)
          atomicAdd(&Lp[wm + ((lane >> 4) << 2) + i * 16 + r], sj);
      }
    __syncthreads();
    if (t < 128) atomicAdd(&Lsum[bm * 128 + t], Lp[t]);
  } else {
#pragma unroll
    for (int i = 0; i < 4; i++)
#pragma unroll
      for (int r = 0; r < 4; r++) {
        const int gr = rowbase + i * 16 + r;
        const float linv = 1.0f / Lsum[gr];
#pragma unroll
        for (int j = 0; j < 4; j++) {
          const int gc = colbase + j * 16;
          const float v = acc[i][j][r] * linv;
          if (single)
            Cf[(size_t)gr * ldc + gc] = v;
          else
            atomicAdd(&Cf[(size_t)gr * ldc + gc], v);
        }
      }
  }
}

// ---------------------------------------------------------------------------
// kernel_launch — 5 launches total.  ws layout (ushort elems):
//   [0,4M)    xb [4096x1024]; after concat GEMM, reused as V^T [1024x4096]
//   [4M,7M)   W_all^T = Wq^T | Wk^T | Wv^T  (3072 x 1024)
//   [7M,19M)  Call [4096x3072] = Q | K | V  (Q pre-scaled by 1/32)
//   [19M,35M) Sb [4096x4096]  (U = exp scores)
//   [35M,..)  ball [3072] f32, Lsum [4096] f32
// ---------------------------------------------------------------------------
extern "C" void kernel_launch(void* const* d_in, const int* in_sizes, int n_in,
                              void* d_out, int out_size, void* d_ws,
                              size_t ws_size, hipStream_t stream) {
  (void)in_sizes; (void)n_in; (void)out_size; (void)ws_size;
  const float* x  = (const float*)d_in[0];
  const float* Wq = (const float*)d_in[1];
  const float* bq = (const float*)d_in[2];
  const float* Wk = (const float*)d_in[3];
  const float* bk = (const float*)d_in[4];
  const float* Wv = (const float*)d_in[5];
  const float* bv = (const float*)d_in[6];
  float* out = (float*)d_out;

  const size_t M1 = (size_t)1024 * 1024;
  unsigned short* xb   = (unsigned short*)d_ws;   // 4M elems; later V^T
  unsigned short* Wt   = xb + 4 * M1;             // 3M elems
  unsigned short* Call = Wt + 3 * M1;             // 12M elems
  unsigned short* Sb   = Call + 12 * M1;          // 16M elems
  float* ball          = (float*)(Sb + 16 * M1);  // 3072 f32
  float* Lsum          = ball + 3072;             // 4096 f32

  // 1) all prep in one launch
  prep<<<PB_TOTAL, 256, 0, stream>>>(x, Wq, Wk, Wv, bq, bk, bv, xb, Wt, out,
                                     ball, Lsum);
  // 2) Call = x @ [Wq|Wk|Wv] + ball. 768 blocks.
  gemm_tn<0><<<dim3(24, 32), 256, 0, stream>>>(xb, Wt, Call, ball, nullptr,
                                               DIM, DIM, DIM, 3 * DIM);
  // 3) V^T into the dead xb slot.
  transpose_bf16<<<dim3(32, 128), dim3(32, 8), 0, stream>>>(Call + 2048,
                                                            3 * DIM, xb, N_TOK);
  // 4) U = exp(Q K^T) causal + row sums Lsum.
  gemm_tn<2><<<dim3(32, 32), 256, 0, stream>>>(Call, Call + 1024, Sb, nullptr,
                                               Lsum, DIM, 3 * DIM, 3 * DIM,
                                               N_TOK);
  // 5) O = (U V) / L, split-K over z (4 chunks of 1024).
  gemm_tn<3><<<dim3(8, 32, 4), 256, 0, stream>>>(Sb, xb, out, nullptr, Lsum,
                                                 N_TOK, N_TOK, N_TOK, DIM);
}